// Round 6
// baseline (1199.114 us; speedup 1.0000x reference)
//
#include <hip/hip_runtime.h>

#define BDIM 256
#define GRID 1280                  // 5 blocks/CU x 256 CU -- co-resident by __launch_bounds__(256,5)
#define NWAVES (GRID * (BDIM / 64))  // 5120 wave slots == 5120 work items (exact fit)

struct LevelDesc {
    const float* lp; const float* rp; const float* dp;
    int H, W, nCW, nChunks, base, nPerSide;
};
struct Params {
    LevelDesc lv[4];
    const float* left; const float* right;
    float* l1; float* r1; float* l2; float* r2; float* l3; float* r3;
    double* acc; unsigned int* cnt; float* out;
};

__global__ void init_kernel(double* acc, unsigned int* cnt) {
    if (threadIdx.x < 32) acc[threadIdx.x] = 0.0;
    else if (threadIdx.x == 32) *cnt = 0u;
}

// software grid barrier: monotone phase counter, all GRID blocks co-resident.
__device__ __forceinline__ void gsync(unsigned int* cnt, unsigned int target) {
    __syncthreads();
    if (threadIdx.x == 0) {
        __threadfence();                       // release
        atomicAdd(cnt, 1u);
        while (atomicAdd(cnt, 0u) < target) __builtin_amdgcn_s_sleep(2);
        __threadfence();                       // acquire
    }
    __syncthreads();
}

__device__ void resize_dev(const float* __restrict__ sL, const float* __restrict__ sR,
                           float* __restrict__ dL, float* __restrict__ dR,
                           int BC, int Hs, int Ws, int Hd, int Wd, int tid, int nt) {
    const long long half = (long long)BC * Hd * Wd;
    const float stepy = (float)(Hs - 1) / (float)(Hd - 1);
    const float stepx = (float)(Ws - 1) / (float)(Wd - 1);
    for (long long idx = tid; idx < 2 * half; idx += nt) {
        const float* src = (idx < half) ? sL : sR;
        float* dst = (idx < half) ? dL : dR;
        long long id = (idx < half) ? idx : idx - half;
        int i = (int)(id % Wd);
        long long t = id / Wd;
        int j = (int)(t % Hd);
        int bc = (int)(t / Hd);
        float y = j * stepy;
        float x = i * stepx;
        int y0 = (int)floorf(y);
        int y1 = min(y0 + 1, Hs - 1);
        int x0 = (int)floorf(x);
        int x1 = min(x0 + 1, Ws - 1);
        float wy = y - (float)y0;
        float wx = x - (float)x0;
        const float* s = src + (long long)bc * Hs * Ws;
        float t0 = s[(long long)y0 * Ws + x0] * (1.0f - wy) + s[(long long)y1 * Ws + x0] * wy;
        float t1 = s[(long long)y0 * Ws + x1] * (1.0f - wy) + s[(long long)y1 * Ws + x1] * wy;
        dst[id] = t0 * (1.0f - wx) + t1 * wx;
    }
}

__device__ __forceinline__ float ssim_term(float Sx, float Sy, float Sxx, float Syy, float Sxy) {
    const float C1v = 0.0001f;
    const float C2v = 0.0009f;
    float mux = Sx * (1.0f / 9.0f), muy = Sy * (1.0f / 9.0f);
    float sigx = Sxx * (1.0f / 9.0f) - mux * mux;
    float sigy = Syy * (1.0f / 9.0f) - muy * muy;
    float cov  = Sxy * (1.0f / 9.0f) - mux * muy;
    float num = (2.0f * mux * muy + C1v) * (2.0f * cov + C2v);
    float den = (mux * mux + muy * muy + C1v) * (sigx + sigy + C2v);
    float v = (1.0f - num * __builtin_amdgcn_rcpf(den)) * 0.5f;
    return fminf(fmaxf(v, 0.0f), 1.0f);
}

// One item per wave: (level, side, b, col-window, row-chunk). 2 px/lane,
// vertical-first separable SSIM with pair-partial column sums; L1/LR/smooth fused.
// acc layout: term base {ssim 0, l1 8, lr 16, ds 24} + side*4 + level.
__device__ void mega_dev(const Params& P) {
    const int lane = threadIdx.x & 63;
    const int wid  = threadIdx.x >> 6;
    const int w    = blockIdx.x * (BDIM / 64) + wid;   // 0..NWAVES-1, exact fit

    int level = 0;
    if (w >= P.lv[1].base) level = 1;
    if (w >= P.lv[2].base) level = 2;
    if (w >= P.lv[3].base) level = 3;
    LevelDesc L;
    if (level == 0) L = P.lv[0];
    else if (level == 1) L = P.lv[1];
    else if (level == 2) L = P.lv[2];
    else L = P.lv[3];

    int rel = w - L.base;
    const int side = (rel >= L.nPerSide) ? 1 : 0;
    rel -= side * L.nPerSide;
    const int chunk = rel % L.nChunks;
    const int r3i = rel / L.nChunks;
    const int cw = r3i % L.nCW;
    const int b  = r3i / L.nCW;

    const int H = L.H, W = L.W;
    const long long HW = (long long)H * W;
    const float Wm1f = (float)(W - 1);
    const float sgn = side ? 1.0f : -1.0f;

    const float* xim = (side ? L.rp : L.lp) + (long long)b * 3 * HW;
    const float* sim = (side ? L.lp : L.rp) + (long long)b * 3 * HW;
    const float* dme = L.dp + (long long)b * 2 * HW + (side ? HW : 0);
    const float* dot = L.dp + (long long)b * 2 * HW + (side ? 0 : HW);

    const int base = cw * 126;
    const int c0 = base + 2 * lane;
    const int c1 = c0 + 1;
    const bool in0 = c0 < W, in1 = c1 < W;
    const int cc = min(c0, W - 2) >> 1;
    const float fc0 = (float)c0, fc1 = (float)c1;

    const bool lastW = (cw == L.nCW - 1);
    const bool own0 = in0 && (c0 < base + 126 || lastW);
    const bool own1 = in1 && (c1 < base + 126 || lastW);
    const bool ownS0 = own0 && (c0 <= W - 3);
    const bool ownS1 = own1 && (c1 <= W - 3);

    const int r0 = (chunk * H) / L.nChunks;
    const int r1 = ((chunk + 1) * H) / L.nChunks;
    const int jend = min(r1 + 1, H - 1);

    float Pst[3][5][2], Lst[3][5][2];
#pragma unroll
    for (int c = 0; c < 3; ++c)
#pragma unroll
        for (int s = 0; s < 5; ++s) { Pst[c][s][0] = 0.f; Pst[c][s][1] = 0.f;
                                      Lst[c][s][0] = 0.f; Lst[c][s][1] = 0.f; }
    float pd0 = 0.f, pd1 = 0.f;
    float pxv[3][2] = {{0.f,0.f},{0.f,0.f},{0.f,0.f}};

    float f_ss = 0.f, f_l1 = 0.f, f_lr = 0.f, f_ds = 0.f;

    for (int j = r0; j <= jend; ++j) {
        const long long ro = (long long)j * W;
        float2 dpair = ((const float2*)(dme + ro))[cc];
        float d0 = dpair.x, d1 = dpair.y;

        float xq0 = fmaf(sgn * d0, Wm1f, fc0);
        float xq1 = fmaf(sgn * d1, Wm1f, fc1);
        float xf0 = floorf(xq0), xf1 = floorf(xq1);
        int g0 = (int)xf0, g1 = (int)xf1;
        float t0 = xq0 - xf0, t1 = xq1 - xf1;
        float w00 = (g0 >= 0 && g0 < W)      ? 1.0f - t0 : 0.0f;
        float w01 = (g0 >= -1 && g0 < W - 1) ? t0        : 0.0f;
        float w10 = (g1 >= 0 && g1 < W)      ? 1.0f - t1 : 0.0f;
        float w11 = (g1 >= -1 && g1 < W - 1) ? t1        : 0.0f;
        int a0 = min(max(g0, 0), W - 1);
        int a1 = min(max(g0 + 1, 0), W - 1);
        int b0 = min(max(g1, 0), W - 1);
        int b1 = min(max(g1 + 1, 0), W - 1);

        const float* dor = dot + ro;
        float wv0 = dor[a0] * w00 + dor[a1] * w01;
        float wv1 = dor[b0] * w10 + dor[b1] * w11;

        float xv[3][2], yv[3][2];
#pragma unroll
        for (int c = 0; c < 3; ++c) {
            const float* xr = xim + (long long)c * HW + ro;
            const float* sr = sim + (long long)c * HW + ro;
            float2 xp2 = ((const float2*)xr)[cc];
            xv[c][0] = in0 ? xp2.x : 0.f;
            xv[c][1] = in1 ? xp2.y : 0.f;
            yv[c][0] = sr[a0] * w00 + sr[a1] * w01;
            yv[c][1] = sr[b0] * w10 + sr[b1] * w11;
            if (!in0) yv[c][0] = 0.f;
            if (!in1) yv[c][1] = 0.f;
        }

        const bool rowOwn = j < r1;
        if (rowOwn) {
            if (own0) {
                f_l1 += fabsf(xv[0][0] - yv[0][0]) + fabsf(xv[1][0] - yv[1][0]) + fabsf(xv[2][0] - yv[2][0]);
                f_lr += fabsf(d0 - wv0);
            }
            if (own1) {
                f_l1 += fabsf(xv[0][1] - yv[0][1]) + fabsf(xv[1][1] - yv[1][1]) + fabsf(xv[2][1] - yv[2][1]);
                f_lr += fabsf(d1 - wv1);
            }
        }

        // smoothness x-gradients
        {
            float dn  = __shfl_down(d0, 1);
            float xn0 = __shfl_down(xv[0][0], 1);
            float xn1 = __shfl_down(xv[1][0], 1);
            float xn2 = __shfl_down(xv[2][0], 1);
            if (rowOwn) {
                if (own0 && c0 < W - 1) {
                    float g = fabsf(xv[0][0] - xv[0][1]) + fabsf(xv[1][0] - xv[1][1]) + fabsf(xv[2][0] - xv[2][1]);
                    f_ds += fabsf((d0 - d1) * __expf(-g * (1.0f / 3.0f)));
                }
                if (own1 && c1 < W - 1) {
                    float g = fabsf(xv[0][1] - xn0) + fabsf(xv[1][1] - xn1) + fabsf(xv[2][1] - xn2);
                    f_ds += fabsf((d1 - dn) * __expf(-g * (1.0f / 3.0f)));
                }
            }
        }
        // smoothness y-gradients (prev row in regs)
        if (j > r0 && (j - 1) < r1) {
            if (own0) {
                float g = fabsf(pxv[0][0] - xv[0][0]) + fabsf(pxv[1][0] - xv[1][0]) + fabsf(pxv[2][0] - xv[2][0]);
                f_ds += fabsf((pd0 - d0) * __expf(-g * (1.0f / 3.0f)));
            }
            if (own1) {
                float g = fabsf(pxv[0][1] - xv[0][1]) + fabsf(pxv[1][1] - xv[1][1]) + fabsf(pxv[2][1] - xv[2][1]);
                f_ds += fabsf((pd1 - d1) * __expf(-g * (1.0f / 3.0f)));
            }
        }
        pd0 = d0; pd1 = d1;
#pragma unroll
        for (int c = 0; c < 3; ++c) { pxv[c][0] = xv[c][0]; pxv[c][1] = xv[c][1]; }

        const bool emit = (j >= r0 + 2);  // wave-uniform
#pragma unroll
        for (int c = 0; c < 3; ++c) {
            float cs[5][2];
#pragma unroll
            for (int p = 0; p < 2; ++p) {
                float cx = xv[c][p], cy = yv[c][p];
                float v5[5] = {cx, cy, cx * cx, cy * cy, cx * cy};
#pragma unroll
                for (int s = 0; s < 5; ++s) {
                    cs[s][p] = Pst[c][s][p] + v5[s];
                    Pst[c][s][p] = Lst[c][s][p] + v5[s];
                    Lst[c][s][p] = v5[s];
                }
            }
            if (emit) {
                float w0s[5], w1s[5];
#pragma unroll
                for (int s = 0; s < 5; ++s) {
                    float n0 = __shfl_down(cs[s][0], 1);
                    float n1 = __shfl_down(cs[s][1], 1);
                    w0s[s] = cs[s][0] + cs[s][1] + n0;
                    w1s[s] = cs[s][1] + n0 + n1;
                }
                float ts0 = ssim_term(w0s[0], w0s[1], w0s[2], w0s[3], w0s[4]);
                float ts1 = ssim_term(w1s[0], w1s[1], w1s[2], w1s[3], w1s[4]);
                f_ss += (ownS0 ? ts0 : 0.f) + (ownS1 ? ts1 : 0.f);
            }
        }
    }

    // ---- reduction (block is homogeneous in (level, side) by construction) ----
#pragma unroll
    for (int o = 32; o > 0; o >>= 1) {
        f_ss += __shfl_down(f_ss, o);
        f_l1 += __shfl_down(f_l1, o);
        f_lr += __shfl_down(f_lr, o);
        f_ds += __shfl_down(f_ds, o);
    }
    __shared__ float red[BDIM / 64][4];
    __shared__ int meta[2];
    if (threadIdx.x == 0) { meta[0] = level; meta[1] = side; }
    if (lane == 0) {
        red[wid][0] = f_ss; red[wid][1] = f_l1;
        red[wid][2] = f_lr; red[wid][3] = f_ds;
    }
    __syncthreads();
    if (threadIdx.x < 4) {
        int t = threadIdx.x;
        double s = (double)red[0][t] + (double)red[1][t]
                 + (double)red[2][t] + (double)red[3][t];
        atomicAdd(P.acc + t * 8 + meta[1] * 4 + meta[0], s);
    }
    __syncthreads();
}

__device__ void finalize_dev(double* acc, float* out) {
    const int B = 32, H0 = 256, W0 = 512;
    double a[32];
    for (int i = 0; i < 32; ++i) a[i] = atomicAdd(acc + i, 0.0);  // coherent read
    double AP = 0.0, LR = 0.0, DS = 0.0;
    for (int i = 0; i < 4; ++i) {
        int h = H0 >> i, w = W0 >> i;
        double nss = (double)B * 3.0 * (double)(h - 2) * (double)(w - 2);
        double nl1 = (double)B * 3.0 * (double)h * (double)w;
        double nd  = (double)B * (double)h * (double)w;
        AP += 0.85 * (a[0 + i] / nss) + 0.15 * (a[8 + i] / nl1);
        AP += 0.85 * (a[4 + i] / nss) + 0.15 * (a[12 + i] / nl1);
        LR += a[16 + i] / nd + a[20 + i] / nd;
        double sc = 1.0 / (double)(1 << i);
        DS += (a[24 + i] / nd) * sc + (a[28 + i] / nd) * sc;
    }
    AP *= 0.85;
    DS *= 0.1;
    out[0] = (float)(AP + LR + DS);
    out[1] = (float)AP;
    out[2] = (float)LR;
    out[3] = (float)DS;
}

__global__ void __launch_bounds__(BDIM, 5)
everything_kernel(Params P) {
    const int tid = blockIdx.x * BDIM + threadIdx.x;
    const int nt = GRID * BDIM;
    resize_dev(P.left, P.right, P.l1, P.r1, 96, 256, 512, 128, 256, tid, nt);
    gsync(P.cnt, 1u * GRID);
    resize_dev(P.l1, P.r1, P.l2, P.r2, 96, 128, 256, 64, 128, tid, nt);
    gsync(P.cnt, 2u * GRID);
    resize_dev(P.l2, P.r2, P.l3, P.r3, 96, 64, 128, 32, 64, tid, nt);
    gsync(P.cnt, 3u * GRID);
    mega_dev(P);
    gsync(P.cnt, 4u * GRID);
    if (tid == 0) finalize_dev(P.acc, P.out);
}

// ---------------- host launch ----------------
extern "C" void kernel_launch(void* const* d_in, const int* in_sizes, int n_in,
                              void* d_out, int out_size, void* d_ws, size_t ws_size,
                              hipStream_t stream) {
    const int B = 32;
    const float* dsp[4];
    for (int i = 0; i < 4; ++i) dsp[i] = (const float*)d_in[i];
    const float* left  = (const float*)d_in[4];
    const float* right = (const float*)d_in[5];

    double* acc = (double*)d_ws;
    unsigned int* cnt = (unsigned int*)((char*)d_ws + 256);
    float* buf = (float*)((char*)d_ws + 512);

    Params P;
    P.left = left; P.right = right;
    P.acc = acc; P.cnt = cnt; P.out = (float*)d_out;
    float* cur = buf;
    P.l1 = cur; cur += (long long)B * 3 * 128 * 256;
    P.r1 = cur; cur += (long long)B * 3 * 128 * 256;
    P.l2 = cur; cur += (long long)B * 3 * 64 * 128;
    P.r2 = cur; cur += (long long)B * 3 * 64 * 128;
    P.l3 = cur; cur += (long long)B * 3 * 32 * 64;
    P.r3 = cur; cur += (long long)B * 3 * 32 * 64;

    // Exact-fit item layout: totals 3520 + 1152 + 256 + 192 = 5120 = NWAVES.
    // Per-(level,side) counts divisible by 4 -> blocks homogeneous.
    P.lv[0] = { left,  right, dsp[0], 256, 512, 5, 11,    0, 1760 };
    P.lv[1] = { P.l1,  P.r1,  dsp[1], 128, 256, 3,  6, 3520,  576 };
    P.lv[2] = { P.l2,  P.r2,  dsp[2],  64, 128, 1,  4, 4672,  128 };
    P.lv[3] = { P.l3,  P.r3,  dsp[3],  32,  64, 1,  3, 4928,   96 };

    init_kernel<<<1, 64, 0, stream>>>(acc, cnt);
    everything_kernel<<<GRID, BDIM, 0, stream>>>(P);
}

// Round 7
// 650.045 us; speedup vs baseline: 1.8447x; 1.8447x over previous
//
#include <hip/hip_runtime.h>

#define BDIM 256
#define GRID 1280                    // 1280 blocks x 4 waves = 5120 wave slots = 5120 items
#define W0C 512
#define H0C 256

struct LevelDesc {
    const float* lp; const float* rp; const float* dp;
    int H, W, nCW, nChunks, base, nPerSide;
};
struct Params {
    LevelDesc lv[4];
    double* acc; unsigned int* cnt; float* out;
};
struct PyrParams {
    const float* left; const float* right;
    float* l1; float* r1; float* l2; float* r2; float* l3; float* r3;
    double* acc; unsigned int* cnt;
};

// ---------------- composed pyramid (levels 1..3 directly from level 0) ----------------
// resize chain is linear+separable; compose per-axis weights: level k -> 2^k taps.
template<int LVL>
__device__ __forceinline__ void axis_taps(int i, const int* dims, int* idx, float* w) {
    idx[0] = i; w[0] = 1.0f;
    int n = 1;
#pragma unroll
    for (int l = LVL; l >= 1; --l) {
        const int Hs = dims[l - 1], Hd = dims[l];
        const float step = (float)(Hs - 1) / (float)(Hd - 1);
        int ti[8]; float tw[8];
#pragma unroll
        for (int k = 0; k < 4; ++k) {
            if (k < n) {
                float p = fminf((float)idx[k] * step, (float)(Hs - 1));
                int a = (int)p;
                float t = p - (float)a;
                ti[2 * k]     = a;                 tw[2 * k]     = w[k] * (1.0f - t);
                ti[2 * k + 1] = min(a + 1, Hs - 1); tw[2 * k + 1] = w[k] * t;
            }
        }
        n *= 2;
#pragma unroll
        for (int k = 0; k < 8; ++k) if (k < n) { idx[k] = ti[k]; w[k] = tw[k]; }
    }
}

template<int LVL>
__device__ __forceinline__ float pyr_sample(const float* __restrict__ src, int j, int i) {
    const int yd[4] = {H0C, 128, 64, 32};
    const int xd[4] = {W0C, 256, 128, 64};
    int yi[8]; float yw[8];
    int xi[8]; float xw[8];
    axis_taps<LVL>(j, yd, yi, yw);
    axis_taps<LVL>(i, xd, xi, xw);
    const int N = 1 << LVL;
    float acc = 0.0f;
#pragma unroll
    for (int u = 0; u < N; ++u) {
        const float* row = src + (long long)yi[u] * W0C;
        float s = 0.0f;
#pragma unroll
        for (int v = 0; v < N; ++v) s = fmaf(xw[v], row[xi[v]], s);
        acc = fmaf(yw[u], s, acc);
    }
    return acc;
}

// E1/E2/E3: elements per side at levels 1/2/3 (B*3 planes)
#define E1 3145728LL
#define E2 786432LL
#define E3 196608LL

__global__ void __launch_bounds__(BDIM)
pyramid_kernel(PyrParams Q) {
    if (blockIdx.x == 0) {
        if (threadIdx.x < 32) Q.acc[threadIdx.x] = 0.0;
        else if (threadIdx.x == 32) *Q.cnt = 0u;
    }
    long long idx = (long long)blockIdx.x * BDIM + threadIdx.x;
    if (idx < 2 * E1) {
        int side = idx >= E1;
        long long id = side ? idx - E1 : idx;
        int i = (int)(id & 255), j = (int)((id >> 8) & 127), bc = (int)(id >> 15);
        const float* src = (side ? Q.right : Q.left) + (long long)bc * (H0C * W0C);
        (side ? Q.r1 : Q.l1)[id] = pyr_sample<1>(src, j, i);
    } else if (idx < 2 * (E1 + E2)) {
        long long r = idx - 2 * E1;
        int side = r >= E2;
        long long id = side ? r - E2 : r;
        int i = (int)(id & 127), j = (int)((id >> 7) & 63), bc = (int)(id >> 13);
        const float* src = (side ? Q.right : Q.left) + (long long)bc * (H0C * W0C);
        (side ? Q.r2 : Q.l2)[id] = pyr_sample<2>(src, j, i);
    } else {
        long long r = idx - 2 * (E1 + E2);
        int side = r >= E3;
        long long id = side ? r - E3 : r;
        int i = (int)(id & 63), j = (int)((id >> 6) & 31), bc = (int)(id >> 11);
        const float* src = (side ? Q.right : Q.left) + (long long)bc * (H0C * W0C);
        (side ? Q.r3 : Q.l3)[id] = pyr_sample<3>(src, j, i);
    }
}

// ---------------- fused loss ----------------
__device__ __forceinline__ float ssim_term(float Sx, float Sy, float Sxx, float Syy, float Sxy) {
    const float C1v = 0.0001f;
    const float C2v = 0.0009f;
    float mux = Sx * (1.0f / 9.0f), muy = Sy * (1.0f / 9.0f);
    float sigx = Sxx * (1.0f / 9.0f) - mux * mux;
    float sigy = Syy * (1.0f / 9.0f) - muy * muy;
    float cov  = Sxy * (1.0f / 9.0f) - mux * muy;
    float num = (2.0f * mux * muy + C1v) * (2.0f * cov + C2v);
    float den = (mux * mux + muy * muy + C1v) * (sigx + sigy + C2v);
    float v = (1.0f - num * __builtin_amdgcn_rcpf(den)) * 0.5f;
    return fminf(fmaxf(v, 0.0f), 1.0f);
}

__device__ void finalize_dev(double* __restrict__ acc, float* __restrict__ out) {
    const int B = 32;
    double AP = 0.0, LR = 0.0, DS = 0.0;
    for (int i = 0; i < 4; ++i) {
        int h = H0C >> i, w = W0C >> i;
        double nss = (double)B * 3.0 * (double)(h - 2) * (double)(w - 2);
        double nl1 = (double)B * 3.0 * (double)h * (double)w;
        double nd  = (double)B * (double)h * (double)w;
        double ssl = atomicAdd(acc + 0 + i, 0.0)  + atomicAdd(acc + 4 + i, 0.0);
        double l1l = atomicAdd(acc + 8 + i, 0.0)  + atomicAdd(acc + 12 + i, 0.0);
        double lrl = atomicAdd(acc + 16 + i, 0.0) + atomicAdd(acc + 20 + i, 0.0);
        double dsl = atomicAdd(acc + 24 + i, 0.0) + atomicAdd(acc + 28 + i, 0.0);
        AP += 0.85 * (ssl / nss) + 0.15 * (l1l / nl1);
        LR += lrl / nd;
        DS += (dsl / nd) / (double)(1 << i);
    }
    AP *= 0.85;
    DS *= 0.1;
    out[0] = (float)(AP + LR + DS);
    out[1] = (float)AP;
    out[2] = (float)LR;
    out[3] = (float)DS;
}

// One item per wave: (level, side, b, col-window, row-chunk). 2 px/lane,
// vertical-first separable SSIM (pair-partial column sums in regs),
// L1/LR/smoothness fused. Last finishing block computes the final scalars.
// acc layout: term base {ssim 0, l1 8, lr 16, ds 24} + side*4 + level.
__global__ void __launch_bounds__(BDIM, 5)
mega_kernel(Params P) {
    const int lane = threadIdx.x & 63;
    const int wid  = threadIdx.x >> 6;
    const int w    = blockIdx.x * (BDIM / 64) + wid;   // exact fit: 0..5119

    int level = 0;
    if (w >= P.lv[1].base) level = 1;
    if (w >= P.lv[2].base) level = 2;
    if (w >= P.lv[3].base) level = 3;
    LevelDesc L;
    if (level == 0) L = P.lv[0];
    else if (level == 1) L = P.lv[1];
    else if (level == 2) L = P.lv[2];
    else L = P.lv[3];

    int rel = w - L.base;
    const int side = (rel >= L.nPerSide) ? 1 : 0;
    rel -= side * L.nPerSide;
    const int chunk = rel % L.nChunks;
    const int r3i = rel / L.nChunks;
    const int cw = r3i % L.nCW;
    const int b  = r3i / L.nCW;

    const int H = L.H, W = L.W;
    const long long HW = (long long)H * W;
    const float Wm1f = (float)(W - 1);
    const float sgn = side ? 1.0f : -1.0f;

    const float* xim = (side ? L.rp : L.lp) + (long long)b * 3 * HW;
    const float* sim = (side ? L.lp : L.rp) + (long long)b * 3 * HW;
    const float* dme = L.dp + (long long)b * 2 * HW + (side ? HW : 0);
    const float* dot = L.dp + (long long)b * 2 * HW + (side ? 0 : HW);

    const int base = cw * 126;
    const int c0 = base + 2 * lane;
    const int c1 = c0 + 1;
    const bool in0 = c0 < W, in1 = c1 < W;
    const int cc = min(c0, W - 2) >> 1;
    const float fc0 = (float)c0, fc1 = (float)c1;

    const bool lastW = (cw == L.nCW - 1);
    const bool own0 = in0 && (c0 < base + 126 || lastW);
    const bool own1 = in1 && (c1 < base + 126 || lastW);
    const bool ownS0 = own0 && (c0 <= W - 3);
    const bool ownS1 = own1 && (c1 <= W - 3);

    const int r0 = (chunk * H) / L.nChunks;
    const int r1 = ((chunk + 1) * H) / L.nChunks;
    const int jend = min(r1 + 1, H - 1);

    float Pst[3][5][2], Lst[3][5][2];
#pragma unroll
    for (int c = 0; c < 3; ++c)
#pragma unroll
        for (int s = 0; s < 5; ++s) { Pst[c][s][0] = 0.f; Pst[c][s][1] = 0.f;
                                      Lst[c][s][0] = 0.f; Lst[c][s][1] = 0.f; }
    float pd0 = 0.f, pd1 = 0.f;
    float pxv[3][2] = {{0.f,0.f},{0.f,0.f},{0.f,0.f}};

    float f_ss = 0.f, f_l1 = 0.f, f_lr = 0.f, f_ds = 0.f;

    for (int j = r0; j <= jend; ++j) {
        const long long ro = (long long)j * W;
        float2 dpair = ((const float2*)(dme + ro))[cc];
        float d0 = dpair.x, d1 = dpair.y;

        float xq0 = fmaf(sgn * d0, Wm1f, fc0);
        float xq1 = fmaf(sgn * d1, Wm1f, fc1);
        float xf0 = floorf(xq0), xf1 = floorf(xq1);
        int g0 = (int)xf0, g1 = (int)xf1;
        float t0 = xq0 - xf0, t1 = xq1 - xf1;
        float w00 = (g0 >= 0 && g0 < W)      ? 1.0f - t0 : 0.0f;
        float w01 = (g0 >= -1 && g0 < W - 1) ? t0        : 0.0f;
        float w10 = (g1 >= 0 && g1 < W)      ? 1.0f - t1 : 0.0f;
        float w11 = (g1 >= -1 && g1 < W - 1) ? t1        : 0.0f;
        int a0 = min(max(g0, 0), W - 1);
        int a1 = min(max(g0 + 1, 0), W - 1);
        int b0 = min(max(g1, 0), W - 1);
        int b1 = min(max(g1 + 1, 0), W - 1);

        const float* dor = dot + ro;
        float wv0 = dor[a0] * w00 + dor[a1] * w01;
        float wv1 = dor[b0] * w10 + dor[b1] * w11;

        float xv[3][2], yv[3][2];
#pragma unroll
        for (int c = 0; c < 3; ++c) {
            const float* xr = xim + (long long)c * HW + ro;
            const float* sr = sim + (long long)c * HW + ro;
            float2 xp2 = ((const float2*)xr)[cc];
            xv[c][0] = in0 ? xp2.x : 0.f;
            xv[c][1] = in1 ? xp2.y : 0.f;
            yv[c][0] = sr[a0] * w00 + sr[a1] * w01;
            yv[c][1] = sr[b0] * w10 + sr[b1] * w11;
            if (!in0) yv[c][0] = 0.f;
            if (!in1) yv[c][1] = 0.f;
        }

        const bool rowOwn = j < r1;
        if (rowOwn) {
            if (own0) {
                f_l1 += fabsf(xv[0][0] - yv[0][0]) + fabsf(xv[1][0] - yv[1][0]) + fabsf(xv[2][0] - yv[2][0]);
                f_lr += fabsf(d0 - wv0);
            }
            if (own1) {
                f_l1 += fabsf(xv[0][1] - yv[0][1]) + fabsf(xv[1][1] - yv[1][1]) + fabsf(xv[2][1] - yv[2][1]);
                f_lr += fabsf(d1 - wv1);
            }
        }

        // smoothness x-gradients
        {
            float dn  = __shfl_down(d0, 1);
            float xn0 = __shfl_down(xv[0][0], 1);
            float xn1 = __shfl_down(xv[1][0], 1);
            float xn2 = __shfl_down(xv[2][0], 1);
            if (rowOwn) {
                if (own0 && c0 < W - 1) {
                    float g = fabsf(xv[0][0] - xv[0][1]) + fabsf(xv[1][0] - xv[1][1]) + fabsf(xv[2][0] - xv[2][1]);
                    f_ds += fabsf((d0 - d1) * __expf(-g * (1.0f / 3.0f)));
                }
                if (own1 && c1 < W - 1) {
                    float g = fabsf(xv[0][1] - xn0) + fabsf(xv[1][1] - xn1) + fabsf(xv[2][1] - xn2);
                    f_ds += fabsf((d1 - dn) * __expf(-g * (1.0f / 3.0f)));
                }
            }
        }
        // smoothness y-gradients (prev row in regs)
        if (j > r0 && (j - 1) < r1) {
            if (own0) {
                float g = fabsf(pxv[0][0] - xv[0][0]) + fabsf(pxv[1][0] - xv[1][0]) + fabsf(pxv[2][0] - xv[2][0]);
                f_ds += fabsf((pd0 - d0) * __expf(-g * (1.0f / 3.0f)));
            }
            if (own1) {
                float g = fabsf(pxv[0][1] - xv[0][1]) + fabsf(pxv[1][1] - xv[1][1]) + fabsf(pxv[2][1] - xv[2][1]);
                f_ds += fabsf((pd1 - d1) * __expf(-g * (1.0f / 3.0f)));
            }
        }
        pd0 = d0; pd1 = d1;
#pragma unroll
        for (int c = 0; c < 3; ++c) { pxv[c][0] = xv[c][0]; pxv[c][1] = xv[c][1]; }

        const bool emit = (j >= r0 + 2);  // wave-uniform
#pragma unroll
        for (int c = 0; c < 3; ++c) {
            float cs[5][2];
#pragma unroll
            for (int p = 0; p < 2; ++p) {
                float cx = xv[c][p], cy = yv[c][p];
                float v5[5] = {cx, cy, cx * cx, cy * cy, cx * cy};
#pragma unroll
                for (int s = 0; s < 5; ++s) {
                    cs[s][p] = Pst[c][s][p] + v5[s];
                    Pst[c][s][p] = Lst[c][s][p] + v5[s];
                    Lst[c][s][p] = v5[s];
                }
            }
            if (emit) {
                float w0s[5], w1s[5];
#pragma unroll
                for (int s = 0; s < 5; ++s) {
                    float n0 = __shfl_down(cs[s][0], 1);
                    float n1 = __shfl_down(cs[s][1], 1);
                    w0s[s] = cs[s][0] + cs[s][1] + n0;
                    w1s[s] = cs[s][1] + n0 + n1;
                }
                float ts0 = ssim_term(w0s[0], w0s[1], w0s[2], w0s[3], w0s[4]);
                float ts1 = ssim_term(w1s[0], w1s[1], w1s[2], w1s[3], w1s[4]);
                f_ss += (ownS0 ? ts0 : 0.f) + (ownS1 ? ts1 : 0.f);
            }
        }
    }

    // ---- reduction (block homogeneous in (level, side) by construction) ----
#pragma unroll
    for (int o = 32; o > 0; o >>= 1) {
        f_ss += __shfl_down(f_ss, o);
        f_l1 += __shfl_down(f_l1, o);
        f_lr += __shfl_down(f_lr, o);
        f_ds += __shfl_down(f_ds, o);
    }
    __shared__ float red[BDIM / 64][4];
    __shared__ int meta[3];
    if (threadIdx.x == 0) { meta[0] = level; meta[1] = side; }
    if (lane == 0) {
        red[wid][0] = f_ss; red[wid][1] = f_l1;
        red[wid][2] = f_lr; red[wid][3] = f_ds;
    }
    __syncthreads();
    if (threadIdx.x < 4) {
        int t = threadIdx.x;
        double s = (double)red[0][t] + (double)red[1][t]
                 + (double)red[2][t] + (double)red[3][t];
        atomicAdd(P.acc + t * 8 + meta[1] * 4 + meta[0], s);
    }
    __syncthreads();
    // ---- last block finalizes (single increment per block, no spin) ----
    if (threadIdx.x == 0) {
        __threadfence();
        unsigned int old = atomicAdd(P.cnt, 1u);
        meta[2] = (old == (unsigned int)(gridDim.x - 1)) ? 1 : 0;
    }
    __syncthreads();
    if (meta[2] && threadIdx.x == 0) {
        __threadfence();
        finalize_dev(P.acc, P.out);
    }
}

// ---------------- host launch ----------------
extern "C" void kernel_launch(void* const* d_in, const int* in_sizes, int n_in,
                              void* d_out, int out_size, void* d_ws, size_t ws_size,
                              hipStream_t stream) {
    const int B = 32;
    const float* dsp[4];
    for (int i = 0; i < 4; ++i) dsp[i] = (const float*)d_in[i];
    const float* left  = (const float*)d_in[4];
    const float* right = (const float*)d_in[5];

    double* acc = (double*)d_ws;
    unsigned int* cnt = (unsigned int*)((char*)d_ws + 256);
    float* buf = (float*)((char*)d_ws + 512);

    PyrParams Q;
    Q.left = left; Q.right = right; Q.acc = acc; Q.cnt = cnt;
    float* cur = buf;
    Q.l1 = cur; cur += E1;
    Q.r1 = cur; cur += E1;
    Q.l2 = cur; cur += E2;
    Q.r2 = cur; cur += E2;
    Q.l3 = cur; cur += E3;
    Q.r3 = cur; cur += E3;

    Params P;
    P.acc = acc; P.cnt = cnt; P.out = (float*)d_out;
    // Exact-fit items: 3520 + 1152 + 256 + 192 = 5120 = GRID*4.
    // Per-(level,side) counts divisible by 4 -> every block homogeneous.
    P.lv[0] = { left,  right, dsp[0], 256, 512, 5, 11,    0, 1760 };
    P.lv[1] = { Q.l1,  Q.r1,  dsp[1], 128, 256, 3,  6, 3520,  576 };
    P.lv[2] = { Q.l2,  Q.r2,  dsp[2],  64, 128, 1,  4, 4672,  128 };
    P.lv[3] = { Q.l3,  Q.r3,  dsp[3],  32,  64, 1,  3, 4928,   96 };

    const long long totalPyr = 2 * (E1 + E2 + E3);         // 8,257,536
    const int pyrBlocks = (int)(totalPyr / BDIM);          // 32,256 exact
    pyramid_kernel<<<pyrBlocks, BDIM, 0, stream>>>(Q);
    mega_kernel<<<GRID, BDIM, 0, stream>>>(P);
}

// Round 8
// 383.053 us; speedup vs baseline: 3.1304x; 1.6970x over previous
//
#include <hip/hip_runtime.h>

#define BDIM 256
#define GRID 1280                    // 1280 blocks x 4 waves = 5120 wave slots = 5120 items
#define W0C 512
#define H0C 256

struct LevelDesc {
    const float* lp; const float* rp; const float* dp;
    int H, W, nCW, nChunks, base, nPerSide;
};
struct Params {
    LevelDesc lv[4];
    double* acc; unsigned int* cnt; float* out;
};
struct PyrParams {
    const float* left; const float* right;
    float* l1; float* r1; float* l2; float* r2; float* l3; float* r3;
    double* acc; unsigned int* cnt;
};

// ---------------- composed pyramid (levels 1..3 directly from level 0) ----------------
// resize chain is linear+separable; compose per-axis weights: level k -> 2^k taps.
template<int LVL>
__device__ __forceinline__ void axis_taps(int i, const int* dims, int* idx, float* w) {
    idx[0] = i; w[0] = 1.0f;
    int n = 1;
#pragma unroll
    for (int l = LVL; l >= 1; --l) {
        const int Hs = dims[l - 1], Hd = dims[l];
        const float step = (float)(Hs - 1) / (float)(Hd - 1);
        int ti[8]; float tw[8];
#pragma unroll
        for (int k = 0; k < 4; ++k) {
            if (k < n) {
                float p = fminf((float)idx[k] * step, (float)(Hs - 1));
                int a = (int)p;
                float t = p - (float)a;
                ti[2 * k]     = a;                  tw[2 * k]     = w[k] * (1.0f - t);
                ti[2 * k + 1] = min(a + 1, Hs - 1); tw[2 * k + 1] = w[k] * t;
            }
        }
        n *= 2;
#pragma unroll
        for (int k = 0; k < 8; ++k) if (k < n) { idx[k] = ti[k]; w[k] = tw[k]; }
    }
}

template<int LVL>
__device__ __forceinline__ float pyr_sample(const float* __restrict__ src, int j, int i) {
    const int yd[4] = {H0C, 128, 64, 32};
    const int xd[4] = {W0C, 256, 128, 64};
    int yi[8]; float yw[8];
    int xi[8]; float xw[8];
    axis_taps<LVL>(j, yd, yi, yw);
    axis_taps<LVL>(i, xd, xi, xw);
    const int N = 1 << LVL;
    float acc = 0.0f;
#pragma unroll
    for (int u = 0; u < N; ++u) {
        const float* row = src + (long long)yi[u] * W0C;
        float s = 0.0f;
#pragma unroll
        for (int v = 0; v < N; ++v) s = fmaf(xw[v], row[xi[v]], s);
        acc = fmaf(yw[u], s, acc);
    }
    return acc;
}

// E1/E2/E3: elements per side at levels 1/2/3 (B*3 planes)
#define E1 3145728LL
#define E2 786432LL
#define E3 196608LL
// thread counts: level1 2px/thread
#define T1 (E1 / 2)
#define TOTPYR (2 * (T1 + E2 + E3))   // 5,111,808 = 19,968 * 256 exact

__global__ void __launch_bounds__(BDIM)
pyramid_kernel(PyrParams Q) {
    if (blockIdx.x == 0) {
        if (threadIdx.x < 32) Q.acc[threadIdx.x] = 0.0;
        else if (threadIdx.x == 32) *Q.cnt = 0u;
    }
    long long idx = (long long)blockIdx.x * BDIM + threadIdx.x;
    if (idx < 2 * T1) {
        int side = idx >= T1;
        long long id = side ? idx - T1 : idx;               // (bc, j, i2) row-major, w=128
        int i2 = (int)(id & 127), j = (int)((id >> 7) & 127), bc = (int)(id >> 14);
        const float* src = (side ? Q.right : Q.left) + (long long)bc * (H0C * W0C);
        float2 o;
        o.x = pyr_sample<1>(src, j, 2 * i2);
        o.y = pyr_sample<1>(src, j, 2 * i2 + 1);
        ((float2*)(side ? Q.r1 : Q.l1))[id] = o;
    } else if (idx < 2 * T1 + 2 * E2) {
        long long r = idx - 2 * T1;
        int side = r >= E2;
        long long id = side ? r - E2 : r;
        int i = (int)(id & 127), j = (int)((id >> 7) & 63), bc = (int)(id >> 13);
        const float* src = (side ? Q.right : Q.left) + (long long)bc * (H0C * W0C);
        (side ? Q.r2 : Q.l2)[id] = pyr_sample<2>(src, j, i);
    } else {
        long long r = idx - 2 * T1 - 2 * E2;
        int side = r >= E3;
        long long id = side ? r - E3 : r;
        int i = (int)(id & 63), j = (int)((id >> 6) & 31), bc = (int)(id >> 11);
        const float* src = (side ? Q.right : Q.left) + (long long)bc * (H0C * W0C);
        (side ? Q.r3 : Q.l3)[id] = pyr_sample<3>(src, j, i);
    }
}

// ---------------- fused loss ----------------
__device__ __forceinline__ float ssim_term(float Sx, float Sy, float Sxx, float Syy, float Sxy) {
    const float C1v = 0.0001f;
    const float C2v = 0.0009f;
    float mux = Sx * (1.0f / 9.0f), muy = Sy * (1.0f / 9.0f);
    float sigx = Sxx * (1.0f / 9.0f) - mux * mux;
    float sigy = Syy * (1.0f / 9.0f) - muy * muy;
    float cov  = Sxy * (1.0f / 9.0f) - mux * muy;
    float num = (2.0f * mux * muy + C1v) * (2.0f * cov + C2v);
    float den = (mux * mux + muy * muy + C1v) * (sigx + sigy + C2v);
    float v = (1.0f - num * __builtin_amdgcn_rcpf(den)) * 0.5f;
    return fminf(fmaxf(v, 0.0f), 1.0f);
}

__device__ void finalize_dev(double* __restrict__ acc, float* __restrict__ out) {
    const int B = 32;
    double AP = 0.0, LR = 0.0, DS = 0.0;
    for (int i = 0; i < 4; ++i) {
        int h = H0C >> i, w = W0C >> i;
        double nss = (double)B * 3.0 * (double)(h - 2) * (double)(w - 2);
        double nl1 = (double)B * 3.0 * (double)h * (double)w;
        double nd  = (double)B * (double)h * (double)w;
        double ssl = atomicAdd(acc + 0 + i, 0.0)  + atomicAdd(acc + 4 + i, 0.0);
        double l1l = atomicAdd(acc + 8 + i, 0.0)  + atomicAdd(acc + 12 + i, 0.0);
        double lrl = atomicAdd(acc + 16 + i, 0.0) + atomicAdd(acc + 20 + i, 0.0);
        double dsl = atomicAdd(acc + 24 + i, 0.0) + atomicAdd(acc + 28 + i, 0.0);
        AP += 0.85 * (ssl / nss) + 0.15 * (l1l / nl1);
        LR += lrl / nd;
        DS += (dsl / nd) / (double)(1 << i);
    }
    AP *= 0.85;
    DS *= 0.1;
    out[0] = (float)(AP + LR + DS);
    out[1] = (float)AP;
    out[2] = (float)LR;
    out[3] = (float)DS;
}

// One item per wave: (level, side, b, col-window, row-chunk). 2 px/lane,
// vertical-first separable SSIM (pair-partial column sums in regs),
// L1/LR/smoothness fused. Last finishing block computes the final scalars.
// NOTE: plain __launch_bounds__(BDIM) -- a min-waves clause of 5 capped VGPR at
// ~100 and spilled the 60-float SSIM state (R7: 412 MB scratch writes, 3x slower).
__global__ void __launch_bounds__(BDIM)
mega_kernel(Params P) {
    const int lane = threadIdx.x & 63;
    const int wid  = threadIdx.x >> 6;
    const int w    = blockIdx.x * (BDIM / 64) + wid;   // exact fit: 0..5119

    int level = 0;
    if (w >= P.lv[1].base) level = 1;
    if (w >= P.lv[2].base) level = 2;
    if (w >= P.lv[3].base) level = 3;
    LevelDesc L;
    if (level == 0) L = P.lv[0];
    else if (level == 1) L = P.lv[1];
    else if (level == 2) L = P.lv[2];
    else L = P.lv[3];

    int rel = w - L.base;
    const int side = (rel >= L.nPerSide) ? 1 : 0;
    rel -= side * L.nPerSide;
    const int chunk = rel % L.nChunks;
    const int r3i = rel / L.nChunks;
    const int cw = r3i % L.nCW;
    const int b  = r3i / L.nCW;

    const int H = L.H, W = L.W;
    const long long HW = (long long)H * W;
    const float Wm1f = (float)(W - 1);
    const float sgn = side ? 1.0f : -1.0f;

    const float* xim = (side ? L.rp : L.lp) + (long long)b * 3 * HW;
    const float* sim = (side ? L.lp : L.rp) + (long long)b * 3 * HW;
    const float* dme = L.dp + (long long)b * 2 * HW + (side ? HW : 0);
    const float* dot = L.dp + (long long)b * 2 * HW + (side ? 0 : HW);

    const int base = cw * 126;
    const int c0 = base + 2 * lane;
    const int c1 = c0 + 1;
    const bool in0 = c0 < W, in1 = c1 < W;
    const int cc = min(c0, W - 2) >> 1;
    const float fc0 = (float)c0, fc1 = (float)c1;

    const bool lastW = (cw == L.nCW - 1);
    const bool own0 = in0 && (c0 < base + 126 || lastW);
    const bool own1 = in1 && (c1 < base + 126 || lastW);
    const bool ownS0 = own0 && (c0 <= W - 3);
    const bool ownS1 = own1 && (c1 <= W - 3);

    const int r0 = (chunk * H) / L.nChunks;
    const int r1 = ((chunk + 1) * H) / L.nChunks;
    const int jend = min(r1 + 1, H - 1);

    float Pst[3][5][2], Lst[3][5][2];
#pragma unroll
    for (int c = 0; c < 3; ++c)
#pragma unroll
        for (int s = 0; s < 5; ++s) { Pst[c][s][0] = 0.f; Pst[c][s][1] = 0.f;
                                      Lst[c][s][0] = 0.f; Lst[c][s][1] = 0.f; }
    float pd0 = 0.f, pd1 = 0.f;
    float pxv[3][2] = {{0.f,0.f},{0.f,0.f},{0.f,0.f}};

    float f_ss = 0.f, f_l1 = 0.f, f_lr = 0.f, f_ds = 0.f;

    for (int j = r0; j <= jend; ++j) {
        const long long ro = (long long)j * W;
        float2 dpair = ((const float2*)(dme + ro))[cc];
        float d0 = dpair.x, d1 = dpair.y;

        float xq0 = fmaf(sgn * d0, Wm1f, fc0);
        float xq1 = fmaf(sgn * d1, Wm1f, fc1);
        float xf0 = floorf(xq0), xf1 = floorf(xq1);
        int g0 = (int)xf0, g1 = (int)xf1;
        float t0 = xq0 - xf0, t1 = xq1 - xf1;
        float w00 = (g0 >= 0 && g0 < W)      ? 1.0f - t0 : 0.0f;
        float w01 = (g0 >= -1 && g0 < W - 1) ? t0        : 0.0f;
        float w10 = (g1 >= 0 && g1 < W)      ? 1.0f - t1 : 0.0f;
        float w11 = (g1 >= -1 && g1 < W - 1) ? t1        : 0.0f;
        int a0 = min(max(g0, 0), W - 1);
        int a1 = min(max(g0 + 1, 0), W - 1);
        int b0 = min(max(g1, 0), W - 1);
        int b1 = min(max(g1 + 1, 0), W - 1);

        const float* dor = dot + ro;
        float wv0 = dor[a0] * w00 + dor[a1] * w01;
        float wv1 = dor[b0] * w10 + dor[b1] * w11;

        float xv[3][2], yv[3][2];
#pragma unroll
        for (int c = 0; c < 3; ++c) {
            const float* xr = xim + (long long)c * HW + ro;
            const float* sr = sim + (long long)c * HW + ro;
            float2 xp2 = ((const float2*)xr)[cc];
            xv[c][0] = in0 ? xp2.x : 0.f;
            xv[c][1] = in1 ? xp2.y : 0.f;
            yv[c][0] = sr[a0] * w00 + sr[a1] * w01;
            yv[c][1] = sr[b0] * w10 + sr[b1] * w11;
            if (!in0) yv[c][0] = 0.f;
            if (!in1) yv[c][1] = 0.f;
        }

        const bool rowOwn = j < r1;
        if (rowOwn) {
            if (own0) {
                f_l1 += fabsf(xv[0][0] - yv[0][0]) + fabsf(xv[1][0] - yv[1][0]) + fabsf(xv[2][0] - yv[2][0]);
                f_lr += fabsf(d0 - wv0);
            }
            if (own1) {
                f_l1 += fabsf(xv[0][1] - yv[0][1]) + fabsf(xv[1][1] - yv[1][1]) + fabsf(xv[2][1] - yv[2][1]);
                f_lr += fabsf(d1 - wv1);
            }
        }

        // smoothness x-gradients
        {
            float dn  = __shfl_down(d0, 1);
            float xn0 = __shfl_down(xv[0][0], 1);
            float xn1 = __shfl_down(xv[1][0], 1);
            float xn2 = __shfl_down(xv[2][0], 1);
            if (rowOwn) {
                if (own0 && c0 < W - 1) {
                    float g = fabsf(xv[0][0] - xv[0][1]) + fabsf(xv[1][0] - xv[1][1]) + fabsf(xv[2][0] - xv[2][1]);
                    f_ds += fabsf((d0 - d1) * __expf(-g * (1.0f / 3.0f)));
                }
                if (own1 && c1 < W - 1) {
                    float g = fabsf(xv[0][1] - xn0) + fabsf(xv[1][1] - xn1) + fabsf(xv[2][1] - xn2);
                    f_ds += fabsf((d1 - dn) * __expf(-g * (1.0f / 3.0f)));
                }
            }
        }
        // smoothness y-gradients (prev row in regs)
        if (j > r0 && (j - 1) < r1) {
            if (own0) {
                float g = fabsf(pxv[0][0] - xv[0][0]) + fabsf(pxv[1][0] - xv[1][0]) + fabsf(pxv[2][0] - xv[2][0]);
                f_ds += fabsf((pd0 - d0) * __expf(-g * (1.0f / 3.0f)));
            }
            if (own1) {
                float g = fabsf(pxv[0][1] - xv[0][1]) + fabsf(pxv[1][1] - xv[1][1]) + fabsf(pxv[2][1] - xv[2][1]);
                f_ds += fabsf((pd1 - d1) * __expf(-g * (1.0f / 3.0f)));
            }
        }
        pd0 = d0; pd1 = d1;
#pragma unroll
        for (int c = 0; c < 3; ++c) { pxv[c][0] = xv[c][0]; pxv[c][1] = xv[c][1]; }

        const bool emit = (j >= r0 + 2);  // wave-uniform
#pragma unroll
        for (int c = 0; c < 3; ++c) {
            float cs[5][2];
#pragma unroll
            for (int p = 0; p < 2; ++p) {
                float cx = xv[c][p], cy = yv[c][p];
                float v5[5] = {cx, cy, cx * cx, cy * cy, cx * cy};
#pragma unroll
                for (int s = 0; s < 5; ++s) {
                    cs[s][p] = Pst[c][s][p] + v5[s];
                    Pst[c][s][p] = Lst[c][s][p] + v5[s];
                    Lst[c][s][p] = v5[s];
                }
            }
            if (emit) {
                float w0s[5], w1s[5];
#pragma unroll
                for (int s = 0; s < 5; ++s) {
                    float n0 = __shfl_down(cs[s][0], 1);
                    float n1 = __shfl_down(cs[s][1], 1);
                    w0s[s] = cs[s][0] + cs[s][1] + n0;
                    w1s[s] = cs[s][1] + n0 + n1;
                }
                float ts0 = ssim_term(w0s[0], w0s[1], w0s[2], w0s[3], w0s[4]);
                float ts1 = ssim_term(w1s[0], w1s[1], w1s[2], w1s[3], w1s[4]);
                f_ss += (ownS0 ? ts0 : 0.f) + (ownS1 ? ts1 : 0.f);
            }
        }
    }

    // ---- reduction (block homogeneous in (level, side) by construction) ----
#pragma unroll
    for (int o = 32; o > 0; o >>= 1) {
        f_ss += __shfl_down(f_ss, o);
        f_l1 += __shfl_down(f_l1, o);
        f_lr += __shfl_down(f_lr, o);
        f_ds += __shfl_down(f_ds, o);
    }
    __shared__ float red[BDIM / 64][4];
    __shared__ int meta[3];
    if (threadIdx.x == 0) { meta[0] = level; meta[1] = side; }
    if (lane == 0) {
        red[wid][0] = f_ss; red[wid][1] = f_l1;
        red[wid][2] = f_lr; red[wid][3] = f_ds;
    }
    __syncthreads();
    if (threadIdx.x < 4) {
        int t = threadIdx.x;
        double s = (double)red[0][t] + (double)red[1][t]
                 + (double)red[2][t] + (double)red[3][t];
        atomicAdd(P.acc + t * 8 + meta[1] * 4 + meta[0], s);
    }
    __syncthreads();
    // ---- last block finalizes (single increment per block, no spin) ----
    if (threadIdx.x == 0) {
        __threadfence();
        unsigned int old = atomicAdd(P.cnt, 1u);
        meta[2] = (old == (unsigned int)(gridDim.x - 1)) ? 1 : 0;
    }
    __syncthreads();
    if (meta[2] && threadIdx.x == 0) {
        __threadfence();
        finalize_dev(P.acc, P.out);
    }
}

// ---------------- host launch ----------------
extern "C" void kernel_launch(void* const* d_in, const int* in_sizes, int n_in,
                              void* d_out, int out_size, void* d_ws, size_t ws_size,
                              hipStream_t stream) {
    const int B = 32;
    const float* dsp[4];
    for (int i = 0; i < 4; ++i) dsp[i] = (const float*)d_in[i];
    const float* left  = (const float*)d_in[4];
    const float* right = (const float*)d_in[5];

    double* acc = (double*)d_ws;
    unsigned int* cnt = (unsigned int*)((char*)d_ws + 256);
    float* buf = (float*)((char*)d_ws + 512);

    PyrParams Q;
    Q.left = left; Q.right = right; Q.acc = acc; Q.cnt = cnt;
    float* cur = buf;
    Q.l1 = cur; cur += E1;
    Q.r1 = cur; cur += E1;
    Q.l2 = cur; cur += E2;
    Q.r2 = cur; cur += E2;
    Q.l3 = cur; cur += E3;
    Q.r3 = cur; cur += E3;

    Params P;
    P.acc = acc; P.cnt = cnt; P.out = (float*)d_out;
    // Exact-fit items: 3520 + 1152 + 256 + 192 = 5120 = GRID*4.
    // Per-(level,side) counts divisible by 4 -> every block homogeneous.
    P.lv[0] = { left,  right, dsp[0], 256, 512, 5, 11,    0, 1760 };
    P.lv[1] = { Q.l1,  Q.r1,  dsp[1], 128, 256, 3,  6, 3520,  576 };
    P.lv[2] = { Q.l2,  Q.r2,  dsp[2],  64, 128, 1,  4, 4672,  128 };
    P.lv[3] = { Q.l3,  Q.r3,  dsp[3],  32,  64, 1,  3, 4928,   96 };

    const int pyrBlocks = (int)(TOTPYR / BDIM);            // 19,968 exact
    pyramid_kernel<<<pyrBlocks, BDIM, 0, stream>>>(Q);
    mega_kernel<<<GRID, BDIM, 0, stream>>>(P);
}

// Round 9
// 346.977 us; speedup vs baseline: 3.4559x; 1.1040x over previous
//
#include <hip/hip_runtime.h>

#define BDIM 256
#define GRID 1024                    // 1024 blocks x 4 waves = 4096 items = measured resident capacity
#define W0C 512
#define H0C 256

struct LevelDesc {
    const float* lp; const float* rp; const float* dp;
    int H, W, nCW, nChunks, base, nPerSide;
};
struct Params {
    LevelDesc lv[4];
    double* acc; unsigned int* cnt; float* out;
};
struct PyrParams {
    const float* left; const float* right;
    float* l1; float* r1; float* l2; float* r2; float* l3; float* r3;
    double* acc; unsigned int* cnt;
};

// E1/E2/E3: elements per side at levels 1/2/3 (B*3 planes)
#define E1 3145728LL
#define E2 786432LL
#define E3 196608LL
#define T1 (E1 / 2)                  // level-1 threads: 2 px each

// ---------------- K1: level 1 from level 0 (exact chain step, 4 taps) ----------------
__device__ __forceinline__ float samp1(const float* __restrict__ src, int j, int i) {
    const float sy = 255.0f / 127.0f;   // (H0-1)/(H1-1)
    const float sx = 511.0f / 255.0f;
    float y = fminf(j * sy, 255.0f);
    float x = fminf(i * sx, 511.0f);
    int y0 = (int)y, x0 = (int)x;
    int y1 = min(y0 + 1, 255), x1 = min(x0 + 1, 511);
    float wy = y - (float)y0, wx = x - (float)x0;
    const float* r0 = src + (long long)y0 * W0C;
    const float* r1 = src + (long long)y1 * W0C;
    float t0 = r0[x0] * (1.0f - wy) + r1[x0] * wy;
    float t1 = r0[x1] * (1.0f - wy) + r1[x1] * wy;
    return t0 * (1.0f - wx) + t1 * wx;
}

__global__ void __launch_bounds__(BDIM)
pyr1_kernel(PyrParams Q) {
    if (blockIdx.x == 0) {
        if (threadIdx.x < 32) Q.acc[threadIdx.x] = 0.0;
        else if (threadIdx.x == 32) *Q.cnt = 0u;
    }
    long long idx = (long long)blockIdx.x * BDIM + threadIdx.x;
    int side = idx >= T1;
    long long id = side ? idx - T1 : idx;          // (bc, j, i2), w2 = 128
    int i2 = (int)(id & 127), j = (int)((id >> 7) & 127), bc = (int)(id >> 14);
    const float* src = (side ? Q.right : Q.left) + (long long)bc * (H0C * W0C);
    float2 o;
    o.x = samp1(src, j, 2 * i2);
    o.y = samp1(src, j, 2 * i2 + 1);
    ((float2*)(side ? Q.r1 : Q.l1))[id] = o;
}

// ---------------- K2: level 2 (4 taps from L1) + level 3 (16 taps from L1) ----------------
// one-step taps D_dst -> D_src
__device__ __forceinline__ void taps1(int i, int Dd, int Ds, int* idx, float* w) {
    float s = (float)(Ds - 1) / (float)(Dd - 1);
    float p = fminf(i * s, (float)(Ds - 1));
    int a = (int)p; float t = p - (float)a;
    idx[0] = a; w[0] = 1.0f - t;
    idx[1] = min(a + 1, Ds - 1); w[1] = t;
}
// two-step taps D2 -> D1 -> D0
__device__ __forceinline__ void taps2(int i, int D2, int D1, int D0, int* idx, float* w) {
    int i1[2]; float w1[2];
    taps1(i, D2, D1, i1, w1);
#pragma unroll
    for (int k = 0; k < 2; ++k) {
        int t[2]; float u[2];
        taps1(i1[k], D1, D0, t, u);
        idx[2 * k] = t[0];     w[2 * k] = w1[k] * u[0];
        idx[2 * k + 1] = t[1]; w[2 * k + 1] = w1[k] * u[1];
    }
}

__global__ void __launch_bounds__(BDIM)
pyr23_kernel(PyrParams Q) {
    long long idx = (long long)blockIdx.x * BDIM + threadIdx.x;
    if (idx < 2 * E2) {
        int side = idx >= E2;
        long long id = side ? idx - E2 : idx;      // (bc, j, i), 64x128
        int i = (int)(id & 127), j = (int)((id >> 7) & 63), bc = (int)(id >> 13);
        const float* src = (side ? Q.r1 : Q.l1) + (long long)bc * (128 * 256);
        int yi[2], xi[2]; float yw[2], xw[2];
        taps1(j, 64, 128, yi, yw);
        taps1(i, 128, 256, xi, xw);
        float a = 0.0f;
#pragma unroll
        for (int u = 0; u < 2; ++u) {
            const float* row = src + (long long)yi[u] * 256;
            a = fmaf(yw[u], fmaf(xw[0], row[xi[0]], xw[1] * row[xi[1]]), a);
        }
        (side ? Q.r2 : Q.l2)[id] = a;
    } else {
        long long r = idx - 2 * E2;
        int side = r >= E3;
        long long id = side ? r - E3 : r;          // (bc, j, i), 32x64
        int i = (int)(id & 63), j = (int)((id >> 6) & 31), bc = (int)(id >> 11);
        const float* src = (side ? Q.r1 : Q.l1) + (long long)bc * (128 * 256);
        int yi[4], xi[4]; float yw[4], xw[4];
        taps2(j, 32, 64, 128, yi, yw);
        taps2(i, 64, 128, 256, xi, xw);
        float a = 0.0f;
#pragma unroll
        for (int u = 0; u < 4; ++u) {
            const float* row = src + (long long)yi[u] * 256;
            float s = 0.0f;
#pragma unroll
            for (int v = 0; v < 4; ++v) s = fmaf(xw[v], row[xi[v]], s);
            a = fmaf(yw[u], s, a);
        }
        (side ? Q.r3 : Q.l3)[id] = a;
    }
}

// ---------------- fused loss ----------------
__device__ __forceinline__ float ssim_term(float Sx, float Sy, float Sxx, float Syy, float Sxy) {
    const float C1v = 0.0001f;
    const float C2v = 0.0009f;
    float mux = Sx * (1.0f / 9.0f), muy = Sy * (1.0f / 9.0f);
    float sigx = Sxx * (1.0f / 9.0f) - mux * mux;
    float sigy = Syy * (1.0f / 9.0f) - muy * muy;
    float cov  = Sxy * (1.0f / 9.0f) - mux * muy;
    float num = (2.0f * mux * muy + C1v) * (2.0f * cov + C2v);
    float den = (mux * mux + muy * muy + C1v) * (sigx + sigy + C2v);
    float v = (1.0f - num * __builtin_amdgcn_rcpf(den)) * 0.5f;
    return fminf(fmaxf(v, 0.0f), 1.0f);
}

__device__ void finalize_dev(double* __restrict__ acc, float* __restrict__ out) {
    const int B = 32;
    double AP = 0.0, LR = 0.0, DS = 0.0;
    for (int i = 0; i < 4; ++i) {
        int h = H0C >> i, w = W0C >> i;
        double nss = (double)B * 3.0 * (double)(h - 2) * (double)(w - 2);
        double nl1 = (double)B * 3.0 * (double)h * (double)w;
        double nd  = (double)B * (double)h * (double)w;
        double ssl = atomicAdd(acc + 0 + i, 0.0)  + atomicAdd(acc + 4 + i, 0.0);
        double l1l = atomicAdd(acc + 8 + i, 0.0)  + atomicAdd(acc + 12 + i, 0.0);
        double lrl = atomicAdd(acc + 16 + i, 0.0) + atomicAdd(acc + 20 + i, 0.0);
        double dsl = atomicAdd(acc + 24 + i, 0.0) + atomicAdd(acc + 28 + i, 0.0);
        AP += 0.85 * (ssl / nss) + 0.15 * (l1l / nl1);
        LR += lrl / nd;
        DS += (dsl / nd) / (double)(1 << i);
    }
    AP *= 0.85;
    DS *= 0.1;
    out[0] = (float)(AP + LR + DS);
    out[1] = (float)AP;
    out[2] = (float)LR;
    out[3] = (float)DS;
}

// One item per wave: (level, side, b, col-window, row-chunk). 2 px/lane,
// vertical-first separable SSIM; L1/LR/smoothness fused; last block finalizes.
// NOTE: plain __launch_bounds__(BDIM): a min-waves clause spilled 60 floats (R7).
// Work table sized to measured residency: 4096 waves (16/CU at 84 VGPR), ~30
// row-units per item -> single round, no sequential second item (R8 lesson).
__global__ void __launch_bounds__(BDIM)
mega_kernel(Params P) {
    const int lane = threadIdx.x & 63;
    const int wid  = threadIdx.x >> 6;
    const int w    = blockIdx.x * (BDIM / 64) + wid;   // exact fit: 0..4095

    int level = 0;
    if (w >= P.lv[1].base) level = 1;
    if (w >= P.lv[2].base) level = 2;
    if (w >= P.lv[3].base) level = 3;
    LevelDesc L;
    if (level == 0) L = P.lv[0];
    else if (level == 1) L = P.lv[1];
    else if (level == 2) L = P.lv[2];
    else L = P.lv[3];

    int rel = w - L.base;
    const int side = (rel >= L.nPerSide) ? 1 : 0;
    rel -= side * L.nPerSide;
    const int chunk = rel % L.nChunks;
    const int r3i = rel / L.nChunks;
    const int cw = r3i % L.nCW;
    const int b  = r3i / L.nCW;

    const int H = L.H, W = L.W;
    const long long HW = (long long)H * W;
    const float Wm1f = (float)(W - 1);
    const float sgn = side ? 1.0f : -1.0f;

    const float* xim = (side ? L.rp : L.lp) + (long long)b * 3 * HW;
    const float* sim = (side ? L.lp : L.rp) + (long long)b * 3 * HW;
    const float* dme = L.dp + (long long)b * 2 * HW + (side ? HW : 0);
    const float* dot = L.dp + (long long)b * 2 * HW + (side ? 0 : HW);

    const int base = cw * 126;
    const int c0 = base + 2 * lane;
    const int c1 = c0 + 1;
    const bool in0 = c0 < W, in1 = c1 < W;
    const int cc = min(c0, W - 2) >> 1;
    const float fc0 = (float)c0, fc1 = (float)c1;

    const bool lastW = (cw == L.nCW - 1);
    const bool own0 = in0 && (c0 < base + 126 || lastW);
    const bool own1 = in1 && (c1 < base + 126 || lastW);
    const bool ownS0 = own0 && (c0 <= W - 3);
    const bool ownS1 = own1 && (c1 <= W - 3);

    const int r0 = (chunk * H) / L.nChunks;
    const int r1 = ((chunk + 1) * H) / L.nChunks;
    const int jend = min(r1 + 1, H - 1);

    float Pst[3][5][2], Lst[3][5][2];
#pragma unroll
    for (int c = 0; c < 3; ++c)
#pragma unroll
        for (int s = 0; s < 5; ++s) { Pst[c][s][0] = 0.f; Pst[c][s][1] = 0.f;
                                      Lst[c][s][0] = 0.f; Lst[c][s][1] = 0.f; }
    float pd0 = 0.f, pd1 = 0.f;
    float pxv[3][2] = {{0.f,0.f},{0.f,0.f},{0.f,0.f}};

    float f_ss = 0.f, f_l1 = 0.f, f_lr = 0.f, f_ds = 0.f;

    for (int j = r0; j <= jend; ++j) {
        const long long ro = (long long)j * W;
        float2 dpair = ((const float2*)(dme + ro))[cc];
        float d0 = dpair.x, d1 = dpair.y;

        float xq0 = fmaf(sgn * d0, Wm1f, fc0);
        float xq1 = fmaf(sgn * d1, Wm1f, fc1);
        float xf0 = floorf(xq0), xf1 = floorf(xq1);
        int g0 = (int)xf0, g1 = (int)xf1;
        float t0 = xq0 - xf0, t1 = xq1 - xf1;
        float w00 = (g0 >= 0 && g0 < W)      ? 1.0f - t0 : 0.0f;
        float w01 = (g0 >= -1 && g0 < W - 1) ? t0        : 0.0f;
        float w10 = (g1 >= 0 && g1 < W)      ? 1.0f - t1 : 0.0f;
        float w11 = (g1 >= -1 && g1 < W - 1) ? t1        : 0.0f;
        int a0 = min(max(g0, 0), W - 1);
        int a1 = min(max(g0 + 1, 0), W - 1);
        int b0 = min(max(g1, 0), W - 1);
        int b1 = min(max(g1 + 1, 0), W - 1);

        const float* dor = dot + ro;
        float wv0 = dor[a0] * w00 + dor[a1] * w01;
        float wv1 = dor[b0] * w10 + dor[b1] * w11;

        float xv[3][2], yv[3][2];
#pragma unroll
        for (int c = 0; c < 3; ++c) {
            const float* xr = xim + (long long)c * HW + ro;
            const float* sr = sim + (long long)c * HW + ro;
            float2 xp2 = ((const float2*)xr)[cc];
            xv[c][0] = in0 ? xp2.x : 0.f;
            xv[c][1] = in1 ? xp2.y : 0.f;
            yv[c][0] = sr[a0] * w00 + sr[a1] * w01;
            yv[c][1] = sr[b0] * w10 + sr[b1] * w11;
            if (!in0) yv[c][0] = 0.f;
            if (!in1) yv[c][1] = 0.f;
        }

        const bool rowOwn = j < r1;
        if (rowOwn) {
            if (own0) {
                f_l1 += fabsf(xv[0][0] - yv[0][0]) + fabsf(xv[1][0] - yv[1][0]) + fabsf(xv[2][0] - yv[2][0]);
                f_lr += fabsf(d0 - wv0);
            }
            if (own1) {
                f_l1 += fabsf(xv[0][1] - yv[0][1]) + fabsf(xv[1][1] - yv[1][1]) + fabsf(xv[2][1] - yv[2][1]);
                f_lr += fabsf(d1 - wv1);
            }
        }

        // smoothness x-gradients
        {
            float dn  = __shfl_down(d0, 1);
            float xn0 = __shfl_down(xv[0][0], 1);
            float xn1 = __shfl_down(xv[1][0], 1);
            float xn2 = __shfl_down(xv[2][0], 1);
            if (rowOwn) {
                if (own0 && c0 < W - 1) {
                    float g = fabsf(xv[0][0] - xv[0][1]) + fabsf(xv[1][0] - xv[1][1]) + fabsf(xv[2][0] - xv[2][1]);
                    f_ds += fabsf((d0 - d1) * __expf(-g * (1.0f / 3.0f)));
                }
                if (own1 && c1 < W - 1) {
                    float g = fabsf(xv[0][1] - xn0) + fabsf(xv[1][1] - xn1) + fabsf(xv[2][1] - xn2);
                    f_ds += fabsf((d1 - dn) * __expf(-g * (1.0f / 3.0f)));
                }
            }
        }
        // smoothness y-gradients (prev row in regs)
        if (j > r0 && (j - 1) < r1) {
            if (own0) {
                float g = fabsf(pxv[0][0] - xv[0][0]) + fabsf(pxv[1][0] - xv[1][0]) + fabsf(pxv[2][0] - xv[2][0]);
                f_ds += fabsf((pd0 - d0) * __expf(-g * (1.0f / 3.0f)));
            }
            if (own1) {
                float g = fabsf(pxv[0][1] - xv[0][1]) + fabsf(pxv[1][1] - xv[1][1]) + fabsf(pxv[2][1] - xv[2][1]);
                f_ds += fabsf((pd1 - d1) * __expf(-g * (1.0f / 3.0f)));
            }
        }
        pd0 = d0; pd1 = d1;
#pragma unroll
        for (int c = 0; c < 3; ++c) { pxv[c][0] = xv[c][0]; pxv[c][1] = xv[c][1]; }

        const bool emit = (j >= r0 + 2);  // wave-uniform
#pragma unroll
        for (int c = 0; c < 3; ++c) {
            float cs[5][2];
#pragma unroll
            for (int p = 0; p < 2; ++p) {
                float cx = xv[c][p], cy = yv[c][p];
                float v5[5] = {cx, cy, cx * cx, cy * cy, cx * cy};
#pragma unroll
                for (int s = 0; s < 5; ++s) {
                    cs[s][p] = Pst[c][s][p] + v5[s];
                    Pst[c][s][p] = Lst[c][s][p] + v5[s];
                    Lst[c][s][p] = v5[s];
                }
            }
            if (emit) {
                float w0s[5], w1s[5];
#pragma unroll
                for (int s = 0; s < 5; ++s) {
                    float n0 = __shfl_down(cs[s][0], 1);
                    float n1 = __shfl_down(cs[s][1], 1);
                    w0s[s] = cs[s][0] + cs[s][1] + n0;
                    w1s[s] = cs[s][1] + n0 + n1;
                }
                float ts0 = ssim_term(w0s[0], w0s[1], w0s[2], w0s[3], w0s[4]);
                float ts1 = ssim_term(w1s[0], w1s[1], w1s[2], w1s[3], w1s[4]);
                f_ss += (ownS0 ? ts0 : 0.f) + (ownS1 ? ts1 : 0.f);
            }
        }
    }

    // ---- reduction (block homogeneous in (level, side) by construction) ----
#pragma unroll
    for (int o = 32; o > 0; o >>= 1) {
        f_ss += __shfl_down(f_ss, o);
        f_l1 += __shfl_down(f_l1, o);
        f_lr += __shfl_down(f_lr, o);
        f_ds += __shfl_down(f_ds, o);
    }
    __shared__ float red[BDIM / 64][4];
    __shared__ int meta[3];
    if (threadIdx.x == 0) { meta[0] = level; meta[1] = side; }
    if (lane == 0) {
        red[wid][0] = f_ss; red[wid][1] = f_l1;
        red[wid][2] = f_lr; red[wid][3] = f_ds;
    }
    __syncthreads();
    if (threadIdx.x < 4) {
        int t = threadIdx.x;
        double s = (double)red[0][t] + (double)red[1][t]
                 + (double)red[2][t] + (double)red[3][t];
        atomicAdd(P.acc + t * 8 + meta[1] * 4 + meta[0], s);
    }
    __syncthreads();
    // ---- last block finalizes (single increment per block, no spin) ----
    if (threadIdx.x == 0) {
        __threadfence();
        unsigned int old = atomicAdd(P.cnt, 1u);
        meta[2] = (old == (unsigned int)(gridDim.x - 1)) ? 1 : 0;
    }
    __syncthreads();
    if (meta[2] && threadIdx.x == 0) {
        __threadfence();
        finalize_dev(P.acc, P.out);
    }
}

// ---------------- host launch ----------------
extern "C" void kernel_launch(void* const* d_in, const int* in_sizes, int n_in,
                              void* d_out, int out_size, void* d_ws, size_t ws_size,
                              hipStream_t stream) {
    const float* dsp[4];
    for (int i = 0; i < 4; ++i) dsp[i] = (const float*)d_in[i];
    const float* left  = (const float*)d_in[4];
    const float* right = (const float*)d_in[5];

    double* acc = (double*)d_ws;
    unsigned int* cnt = (unsigned int*)((char*)d_ws + 256);
    float* buf = (float*)((char*)d_ws + 512);

    PyrParams Q;
    Q.left = left; Q.right = right; Q.acc = acc; Q.cnt = cnt;
    float* cur = buf;
    Q.l1 = cur; cur += E1;
    Q.r1 = cur; cur += E1;
    Q.l2 = cur; cur += E2;
    Q.r2 = cur; cur += E2;
    Q.l3 = cur; cur += E3;
    Q.r3 = cur; cur += E3;

    Params P;
    P.acc = acc; P.cnt = cnt; P.out = (float*)d_out;
    // Items: L0 2880 + L1 960 + L2 192 + L3 64 = 4096 = GRID*4.
    // All (level,side) boundaries divisible by 4 -> every block homogeneous.
    P.lv[0] = { left,  right, dsp[0], 256, 512, 5, 9,    0, 1440 };
    P.lv[1] = { Q.l1,  Q.r1,  dsp[1], 128, 256, 3, 5, 2880,  480 };
    P.lv[2] = { Q.l2,  Q.r2,  dsp[2],  64, 128, 1, 3, 3840,   96 };
    P.lv[3] = { Q.l3,  Q.r3,  dsp[3],  32,  64, 1, 1, 4032,   32 };

    pyr1_kernel<<<(int)(2 * T1 / BDIM), BDIM, 0, stream>>>(Q);        // 12288 blocks
    pyr23_kernel<<<(int)(2 * (E2 + E3) / BDIM), BDIM, 0, stream>>>(Q); // 7680 blocks
    mega_kernel<<<GRID, BDIM, 0, stream>>>(P);
}